// Round 1
// baseline (86.703 us; speedup 1.0000x reference)
//
#include <hip/hip_runtime.h>

#define BATCH 4
#define T 4096
#define D 128
#define CHUNKS 64              // blocks per batch
#define ROWS 64                // rows per block  (T / CHUNKS)
#define XS_STRIDE 132          // padded LDS stride for stage 2

// ---------------- Stage 1: partial Gram matrices -----------------
// grid = BATCH*CHUNKS blocks of 256 threads.
// Each block: G_part[d1][d2] = sum over its 64 rows of X[t,d1]*X[t,d2].
// Thread tile: rows d1 = ty*8..+8 (contig), cols d2 = {tx*4..+4} u {64+tx*4..+4}
// -> all LDS reads are broadcast/2-way (conflict-free), 64 FMAs per t-step.
__global__ __launch_bounds__(256) void k_partial_g(const float* __restrict__ x,
                                                   float* __restrict__ part) {
    __shared__ float Xs[ROWS * D];           // 32 KB
    const int blk = blockIdx.x;
    const int b = blk / CHUNKS, chunk = blk % CHUNKS;
    const float* xp = x + ((size_t)b * T + (size_t)chunk * ROWS) * D;
    const int tid = threadIdx.x;

    const float4* xp4 = (const float4*)xp;
    float4* Xs4 = (float4*)Xs;
    #pragma unroll
    for (int i = 0; i < (ROWS * D / 4) / 256; i++)
        Xs4[tid + i * 256] = xp4[tid + i * 256];
    __syncthreads();

    const int ty = tid >> 4, tx = tid & 15;
    const int r0 = ty * 8;
    const int c0 = tx * 4;

    float acc[8][8];
    #pragma unroll
    for (int i = 0; i < 8; i++)
        #pragma unroll
        for (int j = 0; j < 8; j++) acc[i][j] = 0.f;

    for (int t = 0; t < ROWS; t++) {
        const float* row = Xs + t * D;
        float a[8], bv[8];
        #pragma unroll
        for (int i = 0; i < 8; i++) a[i] = row[r0 + i];
        #pragma unroll
        for (int j = 0; j < 4; j++) { bv[j] = row[c0 + j]; bv[4 + j] = row[64 + c0 + j]; }
        #pragma unroll
        for (int i = 0; i < 8; i++)
            #pragma unroll
            for (int j = 0; j < 8; j++) acc[i][j] += a[i] * bv[j];
    }

    float* pp = part + (size_t)blk * (D * D);
    #pragma unroll
    for (int i = 0; i < 8; i++) {
        *(float4*)(pp + (r0 + i) * D + c0)      = make_float4(acc[i][0], acc[i][1], acc[i][2], acc[i][3]);
        *(float4*)(pp + (r0 + i) * D + 64 + c0) = make_float4(acc[i][4], acc[i][5], acc[i][6], acc[i][7]);
    }
}

// Atomic fallback variant (only used if ws is too small for partials).
__global__ __launch_bounds__(256) void k_partial_g_atomic(const float* __restrict__ x,
                                                          float* __restrict__ g) {
    __shared__ float Xs[ROWS * D];
    const int blk = blockIdx.x;
    const int b = blk / CHUNKS, chunk = blk % CHUNKS;
    const float* xp = x + ((size_t)b * T + (size_t)chunk * ROWS) * D;
    const int tid = threadIdx.x;
    const float4* xp4 = (const float4*)xp;
    float4* Xs4 = (float4*)Xs;
    #pragma unroll
    for (int i = 0; i < (ROWS * D / 4) / 256; i++)
        Xs4[tid + i * 256] = xp4[tid + i * 256];
    __syncthreads();
    const int ty = tid >> 4, tx = tid & 15;
    const int r0 = ty * 8, c0 = tx * 4;
    float acc[8][8];
    #pragma unroll
    for (int i = 0; i < 8; i++)
        #pragma unroll
        for (int j = 0; j < 8; j++) acc[i][j] = 0.f;
    for (int t = 0; t < ROWS; t++) {
        const float* row = Xs + t * D;
        float a[8], bv[8];
        #pragma unroll
        for (int i = 0; i < 8; i++) a[i] = row[r0 + i];
        #pragma unroll
        for (int j = 0; j < 4; j++) { bv[j] = row[c0 + j]; bv[4 + j] = row[64 + c0 + j]; }
        #pragma unroll
        for (int i = 0; i < 8; i++)
            #pragma unroll
            for (int j = 0; j < 8; j++) acc[i][j] += a[i] * bv[j];
    }
    float* gp = g + (size_t)b * (D * D);
    #pragma unroll
    for (int i = 0; i < 8; i++)
        #pragma unroll
        for (int j = 0; j < 4; j++) {
            atomicAdd(gp + (r0 + i) * D + c0 + j,      acc[i][j]);
            atomicAdd(gp + (r0 + i) * D + 64 + c0 + j, acc[i][4 + j]);
        }
}

// ---------------- Stage 1b: reduce partials -> G -----------------
// grid = BATCH*D*D/256 = 256 blocks. Coalesced strided column sums.
__global__ __launch_bounds__(256) void k_reduce_g(const float* __restrict__ part,
                                                  float* __restrict__ g) {
    const int o = blockIdx.x * 256 + threadIdx.x;   // 0 .. BATCH*D*D
    const int b = o >> 14;                          // / 16384
    const int e = o & 16383;
    const float* p = part + ((size_t)b * CHUNKS) * (D * D) + e;
    float s0 = 0.f, s1 = 0.f, s2 = 0.f, s3 = 0.f;
    #pragma unroll
    for (int c = 0; c < CHUNKS; c += 4) {
        s0 += p[(size_t)(c + 0) * (D * D)];
        s1 += p[(size_t)(c + 1) * (D * D)];
        s2 += p[(size_t)(c + 2) * (D * D)];
        s3 += p[(size_t)(c + 3) * (D * D)];
    }
    g[o] = (s0 + s1) + (s2 + s3);
}

// ---------------- Stage 2: out = X * G ---------------------------
// grid = BATCH*CHUNKS blocks; each computes a 64-row x 128-col tile.
// Thread micro-tile: 4 rows x 8 cols (cols split {tx*4, 64+tx*4}).
// Xs padded to stride 132 so per-k row reads land on distinct banks.
__global__ __launch_bounds__(256) void k_xg(const float* __restrict__ x,
                                            const float* __restrict__ g,
                                            float* __restrict__ out) {
    __shared__ float Xs[ROWS * XS_STRIDE];   // 33.8 KB
    __shared__ float Gs[32 * D];             // 16 KB
    const int blk = blockIdx.x;
    const int b = blk / CHUNKS, chunk = blk % CHUNKS;
    const float* xp = x + ((size_t)b * T + (size_t)chunk * ROWS) * D;
    const int tid = threadIdx.x;

    #pragma unroll
    for (int ii = 0; ii < (ROWS * D / 4) / 256; ii++) {
        int i = tid + ii * 256;
        int t = i >> 5, c4 = i & 31;
        *(float4*)(Xs + t * XS_STRIDE + c4 * 4) = ((const float4*)xp)[i];
    }

    const int ty = tid >> 4, tx = tid & 15;
    const int r0 = ty * 4;
    const int c0 = tx * 4;

    float acc[4][8];
    #pragma unroll
    for (int i = 0; i < 4; i++)
        #pragma unroll
        for (int j = 0; j < 8; j++) acc[i][j] = 0.f;

    const float* gb = g + (size_t)b * (D * D);
    for (int kt = 0; kt < D; kt += 32) {
        __syncthreads();                     // also covers initial Xs fill
        #pragma unroll
        for (int ii = 0; ii < (32 * D / 4) / 256; ii++)
            ((float4*)Gs)[tid + ii * 256] = ((const float4*)(gb + kt * D))[tid + ii * 256];
        __syncthreads();
        #pragma unroll
        for (int kk = 0; kk < 32; kk++) {
            float xa[4], gv[8];
            #pragma unroll
            for (int i = 0; i < 4; i++) xa[i] = Xs[(r0 + i) * XS_STRIDE + kt + kk];
            #pragma unroll
            for (int j = 0; j < 4; j++) { gv[j] = Gs[kk * D + c0 + j]; gv[4 + j] = Gs[kk * D + 64 + c0 + j]; }
            #pragma unroll
            for (int i = 0; i < 4; i++)
                #pragma unroll
                for (int j = 0; j < 8; j++) acc[i][j] += xa[i] * gv[j];
        }
    }

    float* op = out + ((size_t)b * T + (size_t)chunk * ROWS) * D;
    #pragma unroll
    for (int i = 0; i < 4; i++) {
        *(float4*)(op + (r0 + i) * D + c0)      = make_float4(acc[i][0], acc[i][1], acc[i][2], acc[i][3]);
        *(float4*)(op + (r0 + i) * D + 64 + c0) = make_float4(acc[i][4], acc[i][5], acc[i][6], acc[i][7]);
    }
}

extern "C" void kernel_launch(void* const* d_in, const int* in_sizes, int n_in,
                              void* d_out, int out_size, void* d_ws, size_t ws_size,
                              hipStream_t stream) {
    const float* x = (const float*)d_in[0];
    float* out = (float*)d_out;

    const size_t part_elems = (size_t)BATCH * CHUNKS * D * D;   // 4.19M floats
    const size_t g_elems = (size_t)BATCH * D * D;               // 65536 floats
    const size_t need_bytes = (part_elems + g_elems) * sizeof(float);

    if (ws_size >= need_bytes) {
        float* part = (float*)d_ws;
        float* g = part + part_elems;
        k_partial_g<<<BATCH * CHUNKS, 256, 0, stream>>>(x, part);
        k_reduce_g<<<(int)(g_elems / 256), 256, 0, stream>>>(part, g);
        k_xg<<<BATCH * CHUNKS, 256, 0, stream>>>(x, g, out);
    } else {
        // Fallback: atomic accumulation directly into G (needs only 256 KB ws).
        float* g = (float*)d_ws;
        hipMemsetAsync(g, 0, g_elems * sizeof(float), stream);
        k_partial_g_atomic<<<BATCH * CHUNKS, 256, 0, stream>>>(x, g);
        k_xg<<<BATCH * CHUNKS, 256, 0, stream>>>(x, g, out);
    }
}